// Round 4
// baseline (283.747 us; speedup 1.0000x reference)
//
#include <hip/hip_runtime.h>
#include <hip/hip_bf16.h>
#include <stdint.h>

// out[m, o] = sum_k x[m,k] * w[o,k] * scale[o] + bias[o]
// M = 4096 (B*S), N = DOUT = 4096, K = DIN = 4096.
// Weight is delivered by the harness as int32 (one int per int8 value).
#define M_DIM 4096
#define N_DIM 4096
#define K_DIM 4096

typedef unsigned short u16;
typedef __attribute__((ext_vector_type(8))) __bf16 bf16x8;
typedef __attribute__((ext_vector_type(4))) float f32x4;

// ---------------- helpers ----------------

__device__ __forceinline__ uint32_t pack_bf16_rn(float a, float b) {
  uint32_t ua = (__float_as_uint(a) + 0x8000u) >> 16;
  uint32_t ub = (__float_as_uint(b) + 0x8000u) & 0xffff0000u;
  return ua | ub;
}

// small ints (|v|<=128) -> bf16 exact
__device__ __forceinline__ uint32_t pack_bf16_int(int a, int b) {
  uint32_t ha = __float_as_uint((float)a) >> 16;
  uint32_t hb = __float_as_uint((float)b) & 0xffff0000u;
  return ha | hb;
}

// async global->LDS, 16B/lane. LDS dest wave-uniform base (+lane*16 in HW).
__device__ __forceinline__ void gload16(const void* g, void* l) {
  __builtin_amdgcn_global_load_lds(
      (__attribute__((address_space(1))) void*)(uintptr_t)g,
      (__attribute__((address_space(3))) void*)l,
      16, 0, 0);
}

// ---------------- convert kernel ----------------
// ws tile layout (A and B identical): supertile ST (256 rows), k-tile KT (64 k):
// 32KB block at ((ST*64+KT)<<15) bytes = 2048 16B-chunks:
//   chunk = (h<<10) + (r<<3) + (c ^ (r&7))   [T2 swizzle within 128B row]
// Thread handles one (c,r,h,st) and 4 k-tiles (kt0 + 16*i).
__global__ __launch_bounds__(256) void convert_kernel(
    const float* __restrict__ x, const int* __restrict__ w,
    u16* __restrict__ wsA, u16* __restrict__ wsB) {
  uint32_t bid = blockIdx.x;
  bool isA = bid < 2048;
  uint32_t tid = (isA ? bid : (bid - 2048)) * 256u + threadIdx.x;  // [0, 2^19)
  uint32_t c   = tid & 7u;
  uint32_t r   = (tid >> 3) & 127u;
  uint32_t h   = (tid >> 10) & 1u;
  uint32_t kt0 = (tid >> 11) & 15u;
  uint32_t st  = tid >> 15;  // 0..15

  uint32_t row = st * 256u + h * 128u + r;
  uint32_t sc  = c ^ (r & 7u);
  size_t dbase = ((size_t)(h << 10) + (r << 3) + sc) << 4;  // byte offset within tile

  if (isA) {
    const float* srcr = x + ((size_t)row << 12) + c * 8u;
#pragma unroll
    for (int i = 0; i < 4; ++i) {
      uint32_t kt = kt0 + 16u * i;
      const float* src = srcr + ((size_t)kt << 6);
      float4 f0 = *(const float4*)src;
      float4 f1 = *(const float4*)(src + 4);
      uint4 o;
      o.x = pack_bf16_rn(f0.x, f0.y); o.y = pack_bf16_rn(f0.z, f0.w);
      o.z = pack_bf16_rn(f1.x, f1.y); o.w = pack_bf16_rn(f1.z, f1.w);
      *(uint4*)((char*)wsA + (((size_t)(st * 64u + kt)) << 15) + dbase) = o;
    }
  } else {
    const int* srcr = w + ((size_t)row << 12) + c * 8u;
#pragma unroll
    for (int i = 0; i < 4; ++i) {
      uint32_t kt = kt0 + 16u * i;
      const int* src = srcr + ((size_t)kt << 6);
      int4 i0 = *(const int4*)src;
      int4 i1 = *(const int4*)(src + 4);
      uint4 o;
      o.x = pack_bf16_int(i0.x, i0.y); o.y = pack_bf16_int(i0.z, i0.w);
      o.z = pack_bf16_int(i1.x, i1.y); o.w = pack_bf16_int(i1.z, i1.w);
      *(uint4*)((char*)wsB + (((size_t)(st * 64u + kt)) << 15) + dbase) = o;
    }
  }
}

// ---------------- GEMM: 256x256 tile, 8-phase counted-vmcnt pipeline ----------------
// 512 threads = 8 waves (2 wr x 4 wc). Per-wave output 128x64:
// rows mh*128 + wr*64 + m*16, cols nh*128 + wc*32 + n*16.
// LDS: d0 (even k-tiles) @0, d1 (odd) @64KB. Within a dbuf:
//   A-h0 @0, A-h1 @16K, B-h0 @32K, B-h1 @48K.
// Phase = one C-quadrant (mh,nh) x K=64 = 16 MFMA. ds_read fresh frags + stage one
// half-tile per phase; vmcnt(4) only at phases 4 & 8 (before trailing barrier).
#define D0 0
#define D1 65536

__global__ __launch_bounds__(512, 2) void gemm_kernel(
    const u16* __restrict__ wsA, const u16* __restrict__ wsB,
    const float* __restrict__ scale, const float* __restrict__ bias,
    float* __restrict__ out) {
  __shared__ __attribute__((aligned(16))) char smem[131072];

  const int tid   = threadIdx.x;
  const int lane  = tid & 63;
  const int wid   = tid >> 6;   // 0..7
  const int wr    = wid >> 2;   // 0..1
  const int wc    = wid & 3;    // 0..3
  const int r16   = lane & 15;
  const int khalf = lane >> 4;  // 0..3

  // XCD-aware bijective swizzle: each XCD gets a 4(mt) x 8(nt) rectangle.
  const int bid = (int)blockIdx.x;
  const int xcd = bid & 7, s = bid >> 3;
  const int mt = ((xcd >> 1) << 2) | (s >> 3);  // 0..15
  const int nt = ((xcd & 1) << 3) | (s & 7);    // 0..15

  const char* gA = (const char*)wsA + ((size_t)mt << 21);  // 64 tiles * 32KB
  const char* gB = (const char*)wsB + ((size_t)nt << 21);

  // LDS read byte offsets (within a 16KB half)
  int aoff[4][2], boff[2][2];
#pragma unroll
  for (int kk = 0; kk < 2; ++kk) {
    int ch = ((kk * 4 + khalf) ^ (r16 & 7)) << 4;
#pragma unroll
    for (int m = 0; m < 4; ++m)
      aoff[m][kk] = ((wr << 6) + (m << 4) + r16) * 128 + ch;
#pragma unroll
    for (int n = 0; n < 2; ++n)
      boff[n][kk] = ((wc << 5) + (n << 4) + r16) * 128 + ch;
  }

  // staging: half-tile = 16KB = 512 thr x 2 rounds x 16B
  const int su = wid << 10;
  const int sl = su + lane * 16;

#define STAGE(gbase, dstbase)                                   \
  do {                                                          \
    gload16((gbase) + sl,        smem + (dstbase) + su);        \
    gload16((gbase) + sl + 8192, smem + (dstbase) + su + 8192); \
  } while (0)

#define LOAD_A(dbase, hoff)                                                     \
  do {                                                                          \
    _Pragma("unroll") for (int m_ = 0; m_ < 4; ++m_) {                          \
      _Pragma("unroll") for (int kk_ = 0; kk_ < 2; ++kk_) {                     \
        af[m_][kk_] = *(const bf16x8*)(smem + (dbase) + (hoff) + aoff[m_][kk_]);\
      }                                                                         \
    }                                                                           \
  } while (0)

#define LOAD_B(dst, dbase, hoff)                                                \
  do {                                                                          \
    _Pragma("unroll") for (int n_ = 0; n_ < 2; ++n_) {                          \
      _Pragma("unroll") for (int kk_ = 0; kk_ < 2; ++kk_) {                     \
        dst[n_][kk_] = *(const bf16x8*)(smem + (dbase) + (hoff) + boff[n_][kk_]);\
      }                                                                         \
    }                                                                           \
  } while (0)

#define PH_BAR()                                          \
  __builtin_amdgcn_sched_barrier(0);                      \
  __builtin_amdgcn_s_barrier();                           \
  asm volatile("s_waitcnt lgkmcnt(0)" ::: "memory");      \
  __builtin_amdgcn_sched_barrier(0)

#define PH_END()                                          \
  __builtin_amdgcn_sched_barrier(0);                      \
  __builtin_amdgcn_s_barrier()

#define MFMA16(MH, NH, BC)                                                      \
  do {                                                                          \
    __builtin_amdgcn_s_setprio(1);                                              \
    _Pragma("unroll") for (int m_ = 0; m_ < 4; ++m_) {                          \
      _Pragma("unroll") for (int n_ = 0; n_ < 2; ++n_) {                        \
        _Pragma("unroll") for (int kk_ = 0; kk_ < 2; ++kk_) {                   \
          acc[MH][m_][NH][n_] = __builtin_amdgcn_mfma_f32_16x16x32_bf16(        \
              af[m_][kk_], BC[n_][kk_], acc[MH][m_][NH][n_], 0, 0, 0);          \
        }                                                                       \
      }                                                                         \
    }                                                                           \
    __builtin_amdgcn_s_setprio(0);                                              \
  } while (0)

  f32x4 acc[2][4][2][2];
#pragma unroll
  for (int mh = 0; mh < 2; ++mh)
#pragma unroll
    for (int m = 0; m < 4; ++m)
#pragma unroll
      for (int nh = 0; nh < 2; ++nh)
#pragma unroll
        for (int n = 0; n < 2; ++n)
          acc[mh][m][nh][n] = (f32x4){0.f, 0.f, 0.f, 0.f};

  bf16x8 af[4][2];   // current A-half fragments
  bf16x8 bc0[2][2];  // B-h0 fragments (live P1..P3)
  bf16x8 bc1[2][2];  // B-h1 fragments (live P2..P4)

  // Prologue: d0 <- ktile 0 (all 4 halves), d1 <- ktile 1 (A0,B0).
  STAGE(gA,         D0 + 0);      // d0.A0
  STAGE(gB,         D0 + 32768);  // d0.B0
  STAGE(gA + 16384, D0 + 16384);  // d0.A1
  STAGE(gB + 16384, D0 + 49152);  // d0.B1
  STAGE(gA + 32768, D1 + 0);      // d1.A0 (ktile 1)
  STAGE(gB + 32768, D1 + 32768);  // d1.B0
  asm volatile("s_waitcnt vmcnt(4)" ::: "memory");  // d0 fully landed
  __builtin_amdgcn_s_barrier();

  for (int t = 0; t < 32; ++t) {
    const size_t k1 = (size_t)(2 * t + 1) << 15;
    const size_t k2 = (size_t)((2 * t + 2) & 63) << 15;
    const size_t k3 = (size_t)((2 * t + 3) & 63) << 15;

    // P1: d0 quad (0,0); stage d1.A1 <- k1
    LOAD_A(D0, 0);
    LOAD_B(bc0, D0, 32768);
    STAGE(gA + k1 + 16384, D1 + 16384);
    PH_BAR();
    MFMA16(0, 0, bc0);
    PH_END();

    // P2: d0 quad (0,1); stage d1.B1 <- k1
    LOAD_B(bc1, D0, 49152);
    STAGE(gB + k1 + 16384, D1 + 49152);
    PH_BAR();
    MFMA16(0, 1, bc1);
    PH_END();

    // P3: d0 quad (1,0); stage d0.A0 <- k2
    LOAD_A(D0, 16384);
    STAGE(gA + k2, D0 + 0);
    PH_BAR();
    MFMA16(1, 0, bc0);
    PH_END();

    // P4: d0 quad (1,1); stage d0.B0 <- k2; vmcnt(4): d1(k1) fully landed
    STAGE(gB + k2, D0 + 32768);
    PH_BAR();
    MFMA16(1, 1, bc1);
    __builtin_amdgcn_sched_barrier(0);
    asm volatile("s_waitcnt vmcnt(4)" ::: "memory");
    __builtin_amdgcn_s_barrier();

    // P5: d1 quad (0,0); stage d0.A1 <- k2
    LOAD_A(D1, 0);
    LOAD_B(bc0, D1, 32768);
    STAGE(gA + k2 + 16384, D0 + 16384);
    PH_BAR();
    MFMA16(0, 0, bc0);
    PH_END();

    // P6: d1 quad (0,1); stage d0.B1 <- k2
    LOAD_B(bc1, D1, 49152);
    STAGE(gB + k2 + 16384, D0 + 49152);
    PH_BAR();
    MFMA16(0, 1, bc1);
    PH_END();

    // P7: d1 quad (1,0); stage d1.A0 <- k3
    LOAD_A(D1, 16384);
    STAGE(gA + k3, D1 + 0);
    PH_BAR();
    MFMA16(1, 0, bc0);
    PH_END();

    // P8: d1 quad (1,1); stage d1.B0 <- k3; vmcnt(4): d0(k2) fully landed
    STAGE(gB + k3, D1 + 32768);
    PH_BAR();
    MFMA16(1, 1, bc1);
    __builtin_amdgcn_sched_barrier(0);
    asm volatile("s_waitcnt vmcnt(4)" ::: "memory");
    __builtin_amdgcn_s_barrier();
  }

  // Epilogue: out = acc * scale[col] + bias[col]
  // C/D: col = r16, row-in-frag = khalf*4 + j.
#pragma unroll
  for (int nh = 0; nh < 2; ++nh)
#pragma unroll
    for (int n = 0; n < 2; ++n) {
      const int col = (nt << 8) + (nh << 7) + (wc << 5) + (n << 4) + r16;
      const float sv = scale[col];
      const float bb = bias[col];
#pragma unroll
      for (int mh = 0; mh < 2; ++mh)
#pragma unroll
        for (int m = 0; m < 4; ++m) {
          const int row0 = (mt << 8) + (mh << 7) + (wr << 6) + (m << 4) + (khalf << 2);
#pragma unroll
          for (int j = 0; j < 4; ++j)
            out[((size_t)(row0 + j) << 12) + col] = acc[mh][m][nh][n][j] * sv + bb;
        }
    }
#undef STAGE
#undef LOAD_A
#undef LOAD_B
#undef PH_BAR
#undef PH_END
#undef MFMA16
}

// ---------------- fallback (only if ws too small) ----------------
__global__ __launch_bounds__(256) void fallback_kernel(
    const float* __restrict__ x, const int* __restrict__ w,
    const float* __restrict__ scale, const float* __restrict__ bias,
    float* __restrict__ out) {
  size_t t = (size_t)blockIdx.x * 256 + threadIdx.x;
  if (t >= (size_t)M_DIM * N_DIM) return;
  int col = (int)(t & (N_DIM - 1));
  int row = (int)(t >> 12);
  const float* xr = x + ((size_t)row << 12);
  const int* wrow = w + ((size_t)col << 12);
  float acc = 0.f;
  for (int k = 0; k < K_DIM; k += 4) {
    float4 xv = *(const float4*)(xr + k);
    int4 wv = *(const int4*)(wrow + k);
    acc += xv.x * (float)wv.x;
    acc += xv.y * (float)wv.y;
    acc += xv.z * (float)wv.z;
    acc += xv.w * (float)wv.w;
  }
  out[t] = acc * scale[col] + bias[col];
}

// ---------------- launch ----------------
extern "C" void kernel_launch(void* const* d_in, const int* in_sizes, int n_in,
                              void* d_out, int out_size, void* d_ws, size_t ws_size,
                              hipStream_t stream) {
  const float* x     = (const float*)d_in[0];
  const int*   w     = (const int*)d_in[1];   // int8 values as int32
  const float* scale = (const float*)d_in[2];
  const float* bias  = (const float*)d_in[3];
  float*       out   = (float*)d_out;

  if (ws_size >= (size_t)64 * 1024 * 1024) {
    u16* wsA = (u16*)d_ws;
    u16* wsB = wsA + (size_t)M_DIM * K_DIM;  // +32MB

    convert_kernel<<<4096, 256, 0, stream>>>(x, w, wsA, wsB);
    gemm_kernel<<<256, 512, 0, stream>>>(wsA, wsB, scale, bias, out);
  } else {
    fallback_kernel<<<((size_t)M_DIM * N_DIM + 255) / 256, 256, 0, stream>>>(
        x, w, scale, bias, out);
  }
}